// Round 5
// baseline (429.760 us; speedup 1.0000x reference)
//
#include <hip/hip_runtime.h>

#define LRES 128
#define HRES 1024
#define NB 256        // hist/scatter blocks (partition must match between hist_k and scat_tr_k)
#define BTS 1024      // threads for big blocks
#define NBUCK 512     // coarse buckets (Morton top 9 bits of 128^3 lattice)
#define RCAP 8192     // refine in-register cap per bucket (avg ~3906)
#define TELEM 2048    // transpose tile elems (64KB LDS; exactly divides LVOX and PPIX)

static const int LVOX = LRES * LRES * LRES; // 2,097,152
static const int PPIX = HRES * HRES;        // 1,048,576
static const int TV = LVOX + 3 * PPIX;      // 5,242,880 transpose elems

typedef float f32x4 __attribute__((ext_vector_type(4)));
typedef unsigned u32x4 __attribute__((ext_vector_type(4)));

// ---------- helpers ----------

// Replicates reference _to_idx exactly.
__device__ __forceinline__ void to_idx(float c, int size, int& i0, int& i1, float& w) {
    float p = (c + 1.0f) * 0.5f * (float)(size - 1);
    float f = floorf(p);
    w = p - f;
    int i = (int)f;
    i0 = min(max(i, 0), size - 1);
    i1 = min(i0 + 1, size - 1);
}

// float -> bf16 (RNE)
__device__ __forceinline__ unsigned f2bf(float f) {
    unsigned u = __float_as_uint(f);
    return (u + 0x7FFFu + ((u >> 16) & 1u)) >> 16;
}
__device__ __forceinline__ float bflo(unsigned u) { return __uint_as_float(u << 16); }
__device__ __forceinline__ float bfhi(unsigned u) { return __uint_as_float(u & 0xFFFF0000u); }

__device__ __forceinline__ void fma8u(f32x4& a0, f32x4& a1, uint4 q, float w) {
    a0.x = fmaf(bflo(q.x), w, a0.x);
    a0.y = fmaf(bfhi(q.x), w, a0.y);
    a0.z = fmaf(bflo(q.y), w, a0.z);
    a0.w = fmaf(bfhi(q.y), w, a0.w);
    a1.x = fmaf(bflo(q.z), w, a1.x);
    a1.y = fmaf(bfhi(q.z), w, a1.y);
    a1.z = fmaf(bflo(q.w), w, a1.z);
    a1.w = fmaf(bfhi(q.w), w, a1.w);
}

__device__ __forceinline__ unsigned spread3(unsigned x) {
    x &= 0x3FFu;
    x = (x | (x << 16)) & 0x030000FFu;
    x = (x | (x << 8)) & 0x0300F00Fu;
    x = (x | (x << 4)) & 0x030C30C3u;
    x = (x | (x << 2)) & 0x09249249u;
    return x;
}
// 21-bit Morton on a 128^3 lattice over [0,1)^3. bucket = >>12, fine = &4095.
__device__ __forceinline__ unsigned morton21(float x, float y, float z) {
    int px = min(max((int)(x * 128.f), 0), 127);
    int py = min(max((int)(y * 128.f), 0), 127);
    int pz = min(max((int)(z * 128.f), 0), 127);
    return spread3(px) | (spread3(py) << 1) | (spread3(pz) << 2);
}

// async 16B global->LDS (direct DMA, vmcnt-tracked; LDS dest = wave base + lane*16)
__device__ __forceinline__ void gl_lds16(const float* src, float* lds_dst) {
    __builtin_amdgcn_global_load_lds(
        (const __attribute__((address_space(1))) void*)src,
        (__attribute__((address_space(3))) void*)lds_dst, 16, 0, 0);
}

// ---------- stage 1: bucket histogram only (transpose moved to scat_tr_k) ----------
// hmat is BUCKET-major: hmat[c * NB + b] (contiguous per-bucket rows for the scan).
__global__ __launch_bounds__(BTS) void hist_k(const float* __restrict__ xyz,
                                              const int* __restrict__ boundp,
                                              unsigned* __restrict__ hmat, int N) {
    __shared__ unsigned h[NBUCK];
    int b = blockIdx.x;
    for (int i = threadIdx.x; i < NBUCK; i += BTS) h[i] = 0u;
    __syncthreads();
    float invb = 1.0f / (float)boundp[0];
    int NG = (N + 3) >> 2; // 4-point groups
    for (int g = b * BTS + threadIdx.x; g < NG; g += NB * BTS) {
        int n0 = g << 2;
        if (n0 + 4 <= N) {
            f32x4 qa = *(const f32x4*)(xyz + (size_t)n0 * 3);
            f32x4 qb = *(const f32x4*)(xyz + (size_t)n0 * 3 + 4);
            f32x4 qc = *(const f32x4*)(xyz + (size_t)n0 * 3 + 8);
            atomicAdd(&h[morton21(qa.x * invb, qa.y * invb, qa.z * invb) >> 12], 1u);
            atomicAdd(&h[morton21(qa.w * invb, qb.x * invb, qb.y * invb) >> 12], 1u);
            atomicAdd(&h[morton21(qb.z * invb, qb.w * invb, qc.x * invb) >> 12], 1u);
            atomicAdd(&h[morton21(qc.y * invb, qc.z * invb, qc.w * invb) >> 12], 1u);
        } else {
            for (int n = n0; n < N; ++n) {
                float x = xyz[(size_t)3 * n + 0] * invb;
                float y = xyz[(size_t)3 * n + 1] * invb;
                float z = xyz[(size_t)3 * n + 2] * invb;
                atomicAdd(&h[morton21(x, y, z) >> 12], 1u);
            }
        }
    }
    __syncthreads();
    for (int i = threadIdx.x; i < NBUCK; i += BTS)
        hmat[(size_t)i * NB + b] = h[i];
}

// Single block: cross-block prefix per bucket (in place, bucket-major rows so
// each thread streams a contiguous 1KB row via uint4 with 8 loads in flight),
// scan bucket totals, emit bucket_base[NBUCK+1], add base into hmat.
__global__ __launch_bounds__(1024) void offsets_k(unsigned* __restrict__ hmat,
                                                  unsigned* __restrict__ bb) {
    __shared__ unsigned tot[NBUCK];
    __shared__ unsigned cbase[NBUCK];
    int t = threadIdx.x;
    unsigned run = 0;
    if (t < NBUCK) {
        u32x4* row = (u32x4*)(hmat + (size_t)t * NB);
        for (int ch = 0; ch < NB / 32; ++ch) { // 8 chunks of 8 uint4 = 256 vals
            u32x4 q[8];
#pragma unroll
            for (int k = 0; k < 8; ++k) q[k] = row[ch * 8 + k];
#pragma unroll
            for (int k = 0; k < 8; ++k) {
                unsigned v0 = q[k].x, v1 = q[k].y, v2 = q[k].z, v3 = q[k].w;
                q[k].x = run; run += v0;
                q[k].y = run; run += v1;
                q[k].z = run; run += v2;
                q[k].w = run; run += v3;
                row[ch * 8 + k] = q[k];
            }
        }
        tot[t] = run;
    }
    __syncthreads();
    for (int o = 1; o < NBUCK; o <<= 1) {
        unsigned v = 0;
        if (t < NBUCK && t >= o) v = tot[t - o];
        __syncthreads();
        if (t < NBUCK) tot[t] += v;
        __syncthreads();
    }
    if (t < NBUCK) {
        unsigned excl = tot[t] - run;
        cbase[t] = excl;
        bb[t] = excl;
        if (t == NBUCK - 1) bb[NBUCK] = tot[t];
    }
    __syncthreads();
    u32x4* hm4 = (u32x4*)hmat;
    for (int idx = t; idx < NB * NBUCK / 4; idx += 1024) {
        u32x4 q = hm4[idx];
        unsigned cb = cbase[idx >> 6]; // 64 uint4 per bucket row (NB/4)
        q.x += cb; q.y += cb; q.z += cb; q.w += cb;
        hm4[idx] = q;
    }
}

// ---------- fused scatter + transpose ----------
// blocks [0,NB): scatter into 512-bucket order (latency/atomic-bound, low BW).
// blocks [NB,..): bf16 channels-last transpose tiles (DMA/stream-bound).
// Disjoint resource profiles -> co-residency hides each other's stalls and
// removes a whole serial pipeline stage (~90us). Transpose is only consumed
// by sample_srt (stage 5), so running it here keeps all dependencies intact.
__global__ __launch_bounds__(BTS) void scat_tr_k(const float* __restrict__ xyz,
                                                 const int* __restrict__ boundp,
                                                 const float* __restrict__ Lg,
                                                 const float* __restrict__ Hp,
                                                 const unsigned* __restrict__ hmat,
                                                 float4* __restrict__ s1,
                                                 u32x4* __restrict__ gclb,
                                                 u32x4* __restrict__ pclb, int N) {
    __shared__ float stage[8 * TELEM]; // 64 KB; scatter branch aliases first 2KB
    int b = blockIdx.x;
    if (b < NB) {
        unsigned* cnt = (unsigned*)stage;
        for (int i = threadIdx.x; i < NBUCK; i += BTS)
            cnt[i] = hmat[(size_t)i * NB + b];
        __syncthreads();
        float invb = 1.0f / (float)boundp[0];
        int NG = (N + 3) >> 2;
        for (int g = b * BTS + threadIdx.x; g < NG; g += NB * BTS) {
            int n0 = g << 2;
            if (n0 + 4 <= N) {
                f32x4 qa = *(const f32x4*)(xyz + (size_t)n0 * 3);
                f32x4 qb = *(const f32x4*)(xyz + (size_t)n0 * 3 + 4);
                f32x4 qc = *(const f32x4*)(xyz + (size_t)n0 * 3 + 8);
                {
                    float x = qa.x * invb, y = qa.y * invb, z = qa.z * invb;
                    unsigned d = atomicAdd(&cnt[morton21(x, y, z) >> 12], 1u);
                    s1[d] = make_float4(x, y, z, __int_as_float(n0 + 0));
                }
                {
                    float x = qa.w * invb, y = qb.x * invb, z = qb.y * invb;
                    unsigned d = atomicAdd(&cnt[morton21(x, y, z) >> 12], 1u);
                    s1[d] = make_float4(x, y, z, __int_as_float(n0 + 1));
                }
                {
                    float x = qb.z * invb, y = qb.w * invb, z = qc.x * invb;
                    unsigned d = atomicAdd(&cnt[morton21(x, y, z) >> 12], 1u);
                    s1[d] = make_float4(x, y, z, __int_as_float(n0 + 2));
                }
                {
                    float x = qc.y * invb, y = qc.z * invb, z = qc.w * invb;
                    unsigned d = atomicAdd(&cnt[morton21(x, y, z) >> 12], 1u);
                    s1[d] = make_float4(x, y, z, __int_as_float(n0 + 3));
                }
            } else {
                for (int n = n0; n < N; ++n) {
                    float x = xyz[(size_t)3 * n + 0] * invb;
                    float y = xyz[(size_t)3 * n + 1] * invb;
                    float z = xyz[(size_t)3 * n + 2] * invb;
                    unsigned d = atomicAdd(&cnt[morton21(x, y, z) >> 12], 1u);
                    s1[d] = make_float4(x, y, z, __int_as_float(n));
                }
            }
        }
    } else {
        // ---- LDS-staged transpose tile: TELEM contiguous channels-last elems ----
        int tb = b - NB;
        size_t vbase = (size_t)tb * TELEM;
        const float* srcbase;
        size_t cstride;
        u32x4* dst;
        if (vbase < (size_t)LVOX) { // tiles never straddle (TELEM | LVOX, PPIX)
            srcbase = Lg + vbase;
            cstride = LVOX;
            dst = gclb + vbase;
        } else {
            size_t u = vbase - LVOX;
            int p = (int)(u >> 20); // PPIX = 2^20
            size_t r = u & (size_t)(PPIX - 1);
            srcbase = Hp + (size_t)p * 8 * PPIX + r;
            cstride = PPIX;
            dst = pclb + (size_t)p * PPIX + r;
        }
        // Stage 8 ch x TELEM f32 = 64KB as 64 wave-chunks of 1KB.
        // chunk k: channel c = k>>3, sub s = k&7; LDS dest = k*1KB + lane*16.
        int wave = threadIdx.x >> 6;
        int lane = threadIdx.x & 63;
        for (int k = wave; k < 64; k += BTS / 64) {
            int c = k >> 3, s = k & 7;
            gl_lds16(srcbase + (size_t)c * cstride + s * 256 + lane * 4,
                     &stage[k * 256]);
        }
        __syncthreads(); // drains vmcnt (compiler emits vmcnt(0) before barrier)
        int t = threadIdx.x;
#pragma unroll
        for (int e = 0; e < TELEM / BTS; ++e) {
            int v = e * BTS + t;
            unsigned hc[8];
#pragma unroll
            for (int c = 0; c < 8; ++c) hc[c] = f2bf(stage[c * TELEM + v]);
            u32x4 o;
            o.x = hc[0] | (hc[1] << 16);
            o.y = hc[2] | (hc[3] << 16);
            o.z = hc[4] | (hc[5] << 16);
            o.w = hc[6] | (hc[7] << 16);
            dst[v] = o; // 1KB contiguous per wave store; stays L2/L3-hot for sampler
        }
    }
}

// Per-bucket LDS counting sort by fine 12-bit Morton key -> full 128^3 order.
// Records live in registers; LDS only holds the 4096 counters + scan aux.
__global__ __launch_bounds__(1024) void refine_k(const float4* __restrict__ s1,
                                                 const unsigned* __restrict__ bb,
                                                 float4* __restrict__ s2) {
    __shared__ unsigned hist[4096];
    __shared__ unsigned part[1024];
    int b = blockIdx.x;
    unsigned start = bb[b];
    unsigned cnt = bb[b + 1] - start;
    int t = threadIdx.x;
    if (cnt > RCAP) { // statistically unreachable; correctness fallback
        for (unsigned j = t; j < cnt; j += 1024) s2[start + j] = s1[start + j];
        return;
    }
    for (int i = t; i < 4096; i += 1024) hist[i] = 0u;
    __syncthreads();
    float4 rec[RCAP / 1024];
    unsigned key[RCAP / 1024], tick[RCAP / 1024];
#pragma unroll
    for (int k = 0; k < RCAP / 1024; ++k) {
        unsigned j = t + k * 1024u;
        if (j < cnt) {
            rec[k] = s1[start + j];
            key[k] = morton21(rec[k].x, rec[k].y, rec[k].z) & 4095u;
            tick[k] = atomicAdd(&hist[key[k]], 1u);
        }
    }
    __syncthreads();
    unsigned h4[4];
    unsigned s = 0;
#pragma unroll
    for (int k = 0; k < 4; ++k) {
        h4[k] = hist[t * 4 + k];
        s += h4[k];
    }
    part[t] = s;
    __syncthreads();
    for (int o = 1; o < 1024; o <<= 1) {
        unsigned v = (t >= o) ? part[t - o] : 0u;
        __syncthreads();
        part[t] += v;
        __syncthreads();
    }
    unsigned base = part[t] - s;
#pragma unroll
    for (int k = 0; k < 4; ++k) {
        hist[t * 4 + k] = base;
        base += h4[k];
    }
    __syncthreads();
#pragma unroll
    for (int k = 0; k < RCAP / 1024; ++k) {
        unsigned j = t + k * 1024u;
        if (j < cnt) s2[start + hist[key[k]] + tick[k]] = rec[k];
    }
}

// ---------- main sampler (Morton order, bf16 channels-last tables) ----------
// Small blocks dispatched in sorted order = moving window over the tables ->
// near-compulsory FETCH (123MB measured R2). Plain out stores (L2 merges the
// scattered 32B writes to ~63MB; NT stores amplified 8.8x in R3).
__global__ __launch_bounds__(256) void sample_srt(const float4* __restrict__ sorted,
                                                  const uint4* __restrict__ gclb,
                                                  const uint4* __restrict__ pclb,
                                                  float* __restrict__ out, int N) {
    int i = blockIdx.x * blockDim.x + threadIdx.x;
    if (i >= N) return;
    float4 rec = sorted[i];
    float x = rec.x, y = rec.y, z = rec.z;
    int idx = __float_as_int(rec.w);

    int x0, x1, y0, y1, z0, z1;
    float wx, wy, wz;
    to_idx(x, LRES, x0, x1, wx);
    to_idx(y, LRES, y0, y1, wy);
    to_idx(z, LRES, z0, z1, wz);
    const uint4* b00 = gclb + ((size_t)z0 * LRES + y0) * LRES;
    const uint4* b01 = gclb + ((size_t)z0 * LRES + y1) * LRES;
    const uint4* b10 = gclb + ((size_t)z1 * LRES + y0) * LRES;
    const uint4* b11 = gclb + ((size_t)z1 * LRES + y1) * LRES;
    uint4 g0 = b00[x0], g1 = b00[x1], g2 = b01[x0], g3 = b01[x1];
    uint4 g4 = b10[x0], g5 = b10[x1], g6 = b11[x0], g7 = b11[x1];

    const float cw[3] = {x, y, z};
    const float ch[3] = {y, z, x};
    float pww[3], pwh[3];
    uint4 r[12];
#pragma unroll
    for (int p = 0; p < 3; ++p) {
        int w0, w1, h0, h1;
        to_idx(cw[p], HRES, w0, w1, pww[p]);
        to_idx(ch[p], HRES, h0, h1, pwh[p]);
        const uint4* base = pclb + (size_t)p * PPIX;
        const uint4* r0 = base + (size_t)h0 * HRES;
        const uint4* r1 = base + (size_t)h1 * HRES;
        r[4 * p + 0] = r0[w0];
        r[4 * p + 1] = r0[w1];
        r[4 * p + 2] = r1[w0];
        r[4 * p + 3] = r1[w1];
    }

    f32x4 a0 = (f32x4)0.f;
    f32x4 a1 = (f32x4)0.f;
    {
        float ux = 1.f - wx, uy = 1.f - wy, uz = 1.f - wz;
        fma8u(a0, a1, g0, uz * uy * ux);
        fma8u(a0, a1, g1, uz * uy * wx);
        fma8u(a0, a1, g2, uz * wy * ux);
        fma8u(a0, a1, g3, uz * wy * wx);
        fma8u(a0, a1, g4, wz * uy * ux);
        fma8u(a0, a1, g5, wz * uy * wx);
        fma8u(a0, a1, g6, wz * wy * ux);
        fma8u(a0, a1, g7, wz * wy * wx);
    }
#pragma unroll
    for (int p = 0; p < 3; ++p) {
        float ww = pww[p], wh = pwh[p];
        float uw = 1.f - ww, uh = 1.f - wh;
        fma8u(a0, a1, r[4 * p + 0], uh * uw);
        fma8u(a0, a1, r[4 * p + 1], uh * ww);
        fma8u(a0, a1, r[4 * p + 2], wh * uw);
        fma8u(a0, a1, r[4 * p + 3], wh * ww);
    }

    f32x4* o = (f32x4*)(out + (size_t)idx * 8);
    o[0] = a0;
    o[1] = a1;
}

// ---------- fallback (channel-first fp32 direct, known-correct) ----------
__global__ __launch_bounds__(256) void sample_cf(
    const float* __restrict__ xyz, const int* __restrict__ boundp,
    const float* __restrict__ Lg, const float* __restrict__ Hp,
    float* __restrict__ out, int N) {
    int n = blockIdx.x * blockDim.x + threadIdx.x;
    if (n >= N) return;
    float invb = 1.0f / (float)boundp[0];
    float x = xyz[(size_t)3 * n + 0] * invb;
    float y = xyz[(size_t)3 * n + 1] * invb;
    float z = xyz[(size_t)3 * n + 2] * invb;
    float acc[8];
#pragma unroll
    for (int c = 0; c < 8; ++c) acc[c] = 0.f;
    {
        int x0, x1, y0, y1, z0, z1;
        float wx, wy, wz;
        to_idx(x, LRES, x0, x1, wx);
        to_idx(y, LRES, y0, y1, wy);
        to_idx(z, LRES, z0, z1, wz);
        float ux = 1.f - wx, uy = 1.f - wy, uz = 1.f - wz;
        size_t i8[8];
        i8[0] = ((size_t)z0 * LRES + y0) * LRES + x0;
        i8[1] = ((size_t)z0 * LRES + y0) * LRES + x1;
        i8[2] = ((size_t)z0 * LRES + y1) * LRES + x0;
        i8[3] = ((size_t)z0 * LRES + y1) * LRES + x1;
        i8[4] = ((size_t)z1 * LRES + y0) * LRES + x0;
        i8[5] = ((size_t)z1 * LRES + y0) * LRES + x1;
        i8[6] = ((size_t)z1 * LRES + y1) * LRES + x0;
        i8[7] = ((size_t)z1 * LRES + y1) * LRES + x1;
        float w8[8] = {uz * uy * ux, uz * uy * wx, uz * wy * ux, uz * wy * wx,
                       wz * uy * ux, wz * uy * wx, wz * wy * ux, wz * wy * wx};
#pragma unroll
        for (int c = 0; c < 8; ++c) {
            const float* g = Lg + (size_t)c * LVOX;
            float s = 0.f;
#pragma unroll
            for (int k = 0; k < 8; ++k) s = fmaf(g[i8[k]], w8[k], s);
            acc[c] += s;
        }
    }
    {
        const float cw[3] = {x, y, z};
        const float ch[3] = {y, z, x};
        for (int p = 0; p < 3; ++p) {
            int w0, w1, h0, h1;
            float ww, wh;
            to_idx(cw[p], HRES, w0, w1, ww);
            to_idx(ch[p], HRES, h0, h1, wh);
            float uw = 1.f - ww, uh = 1.f - wh;
            size_t i4[4] = {(size_t)h0 * HRES + w0, (size_t)h0 * HRES + w1,
                            (size_t)h1 * HRES + w0, (size_t)h1 * HRES + w1};
            float w4[4] = {uh * uw, uh * ww, wh * uw, wh * ww};
            const float* pb = Hp + (size_t)p * 8 * PPIX;
#pragma unroll
            for (int c = 0; c < 8; ++c) {
                const float* g = pb + (size_t)c * PPIX;
                float s = 0.f;
#pragma unroll
                for (int k = 0; k < 4; ++k) s = fmaf(g[i4[k]], w4[k], s);
                acc[c] += s;
            }
        }
    }
#pragma unroll
    for (int c = 0; c < 8; ++c) out[(size_t)n * 8 + c] = acc[c];
}

extern "C" void kernel_launch(void* const* d_in, const int* in_sizes, int n_in,
                              void* d_out, int out_size, void* d_ws, size_t ws_size,
                              hipStream_t stream) {
    const float* xyz = (const float*)d_in[0];
    const int* bound = (const int*)d_in[1];
    const float* Lg = (const float*)d_in[2]; // [8,128,128,128]
    const float* Hp = (const float*)d_in[3]; // [3,8,1024,1024]
    float* out = (float*)d_out;
    int N = in_sizes[0] / 3;

    size_t off = 0;
    size_t gclb_b = (size_t)LVOX * 16;         // 32 MiB
    size_t pclb_b = (size_t)3 * PPIX * 16;     // 48 MiB
    size_t s1_b = (size_t)N * 16;              // 32 MB
    size_t s2_b = (size_t)N * 16;              // 32 MB
    size_t hmat_b = (size_t)NB * NBUCK * 4;    // 512 KiB
    size_t bb_b = (size_t)(NBUCK + 1) * 4;
    size_t need = gclb_b + pclb_b + s1_b + s2_b + hmat_b + bb_b;

    if (ws_size >= need) {
        char* w = (char*)d_ws;
        u32x4* gclb = (u32x4*)(w + off);       off += gclb_b;
        u32x4* pclb = (u32x4*)(w + off);       off += pclb_b;
        float4* s1 = (float4*)(w + off);       off += s1_b;
        float4* s2 = (float4*)(w + off);       off += s2_b;
        unsigned* hmat = (unsigned*)(w + off); off += hmat_b;
        unsigned* bb = (unsigned*)(w + off);

        hist_k<<<NB, BTS, 0, stream>>>(xyz, bound, hmat, N);
        offsets_k<<<1, 1024, 0, stream>>>(hmat, bb);
        int st_blocks = NB + TV / TELEM; // 256 + 2560
        scat_tr_k<<<st_blocks, BTS, 0, stream>>>(xyz, bound, Lg, Hp, hmat, s1,
                                                 gclb, pclb, N);
        refine_k<<<NBUCK, 1024, 0, stream>>>(s1, bb, s2);
        sample_srt<<<(N + 255) / 256, 256, 0, stream>>>(s2, (const uint4*)gclb,
                                                        (const uint4*)pclb, out, N);
    } else {
        sample_cf<<<(N + 255) / 256, 256, 0, stream>>>(xyz, bound, Lg, Hp, out, N);
    }
}

// Round 6
// 379.513 us; speedup vs baseline: 1.1324x; 1.1324x over previous
//
#include <hip/hip_runtime.h>

#define LRES 128
#define HRES 1024
#define NB 256        // hist/scatter blocks (partition must match across fused kernels)
#define BTS 1024      // threads for big blocks
#define NBUCK 512     // coarse buckets (Morton top 9 bits of 128^3 lattice)
#define RCAP 8192     // refine in-register cap per bucket (avg ~3906)
#define TELEM 2048    // transpose tile elems (64KB LDS; exactly divides LVOX and PPIX)
#define TILES_A 1408  // transpose tiles fused with hist   (k1)
#define TILES_B 1152  // transpose tiles fused with scatter (k3); A+B = TV/TELEM = 2560

static const int LVOX = LRES * LRES * LRES; // 2,097,152
static const int PPIX = HRES * HRES;        // 1,048,576
static const int TV = LVOX + 3 * PPIX;      // 5,242,880 transpose elems

typedef float f32x4 __attribute__((ext_vector_type(4)));
typedef unsigned u32x4 __attribute__((ext_vector_type(4)));

// ---------- helpers ----------

// Replicates reference _to_idx exactly.
__device__ __forceinline__ void to_idx(float c, int size, int& i0, int& i1, float& w) {
    float p = (c + 1.0f) * 0.5f * (float)(size - 1);
    float f = floorf(p);
    w = p - f;
    int i = (int)f;
    i0 = min(max(i, 0), size - 1);
    i1 = min(i0 + 1, size - 1);
}

// float -> bf16 (RNE)
__device__ __forceinline__ unsigned f2bf(float f) {
    unsigned u = __float_as_uint(f);
    return (u + 0x7FFFu + ((u >> 16) & 1u)) >> 16;
}
__device__ __forceinline__ float bflo(unsigned u) { return __uint_as_float(u << 16); }
__device__ __forceinline__ float bfhi(unsigned u) { return __uint_as_float(u & 0xFFFF0000u); }

__device__ __forceinline__ void fma8u(f32x4& a0, f32x4& a1, uint4 q, float w) {
    a0.x = fmaf(bflo(q.x), w, a0.x);
    a0.y = fmaf(bfhi(q.x), w, a0.y);
    a0.z = fmaf(bflo(q.y), w, a0.z);
    a0.w = fmaf(bfhi(q.y), w, a0.w);
    a1.x = fmaf(bflo(q.z), w, a1.x);
    a1.y = fmaf(bfhi(q.z), w, a1.y);
    a1.z = fmaf(bflo(q.w), w, a1.z);
    a1.w = fmaf(bfhi(q.w), w, a1.w);
}

__device__ __forceinline__ unsigned spread3(unsigned x) {
    x &= 0x3FFu;
    x = (x | (x << 16)) & 0x030000FFu;
    x = (x | (x << 8)) & 0x0300F00Fu;
    x = (x | (x << 4)) & 0x030C30C3u;
    x = (x | (x << 2)) & 0x09249249u;
    return x;
}
// 21-bit Morton on a 128^3 lattice over [0,1)^3. bucket = >>12, fine = &4095.
__device__ __forceinline__ unsigned morton21(float x, float y, float z) {
    int px = min(max((int)(x * 128.f), 0), 127);
    int py = min(max((int)(y * 128.f), 0), 127);
    int pz = min(max((int)(z * 128.f), 0), 127);
    return spread3(px) | (spread3(py) << 1) | (spread3(pz) << 2);
}

// async 16B global->LDS (direct DMA, vmcnt-tracked; LDS dest = wave base + lane*16)
__device__ __forceinline__ void gl_lds16(const float* src, float* lds_dst) {
    __builtin_amdgcn_global_load_lds(
        (const __attribute__((address_space(1))) void*)src,
        (__attribute__((address_space(3))) void*)lds_dst, 16, 0, 0);
}

// ---------- shared device bodies for the fused kernels ----------

// bf16 channels-last transpose of tile `tile` (TELEM contiguous elems), LDS-staged.
__device__ __forceinline__ void transpose_tile(int tile, const float* __restrict__ Lg,
                                               const float* __restrict__ Hp,
                                               u32x4* __restrict__ gclb,
                                               u32x4* __restrict__ pclb,
                                               float* stage) {
    size_t vbase = (size_t)tile * TELEM;
    const float* srcbase;
    size_t cstride;
    u32x4* dst;
    if (vbase < (size_t)LVOX) { // tiles never straddle (TELEM | LVOX, PPIX)
        srcbase = Lg + vbase;
        cstride = LVOX;
        dst = gclb + vbase;
    } else {
        size_t u = vbase - LVOX;
        int p = (int)(u >> 20); // PPIX = 2^20
        size_t r = u & (size_t)(PPIX - 1);
        srcbase = Hp + (size_t)p * 8 * PPIX + r;
        cstride = PPIX;
        dst = pclb + (size_t)p * PPIX + r;
    }
    // Stage 8 ch x TELEM f32 = 64KB as 64 wave-chunks of 1KB.
    int wave = threadIdx.x >> 6;
    int lane = threadIdx.x & 63;
    for (int k = wave; k < 64; k += BTS / 64) {
        int c = k >> 3, s = k & 7;
        gl_lds16(srcbase + (size_t)c * cstride + s * 256 + lane * 4,
                 &stage[k * 256]);
    }
    __syncthreads(); // drains vmcnt (compiler emits vmcnt(0) before barrier)
    int t = threadIdx.x;
#pragma unroll
    for (int e = 0; e < TELEM / BTS; ++e) {
        int v = e * BTS + t;
        unsigned hc[8];
#pragma unroll
        for (int c = 0; c < 8; ++c) hc[c] = f2bf(stage[c * TELEM + v]);
        u32x4 o;
        o.x = hc[0] | (hc[1] << 16);
        o.y = hc[2] | (hc[3] << 16);
        o.z = hc[4] | (hc[5] << 16);
        o.w = hc[6] | (hc[7] << 16);
        dst[v] = o; // 1KB contiguous per wave store; stays L2/L3-hot for sampler
    }
}

// ---------- k1: blocks [0,NB) = bucket histogram; rest = transpose tiles [0,TILES_A) ----
// hmat is BUCKET-major: hmat[c * NB + b] (contiguous per-bucket rows for colpfx_k).
__global__ __launch_bounds__(BTS) void prep1_k(const float* __restrict__ xyz,
                                               const int* __restrict__ boundp,
                                               const float* __restrict__ Lg,
                                               const float* __restrict__ Hp,
                                               unsigned* __restrict__ hmat,
                                               u32x4* __restrict__ gclb,
                                               u32x4* __restrict__ pclb, int N) {
    __shared__ float stage[8 * TELEM]; // 64 KB; hist branch aliases first 2KB
    int b = blockIdx.x;
    if (b < NB) {
        unsigned* h = (unsigned*)stage;
        for (int i = threadIdx.x; i < NBUCK; i += BTS) h[i] = 0u;
        __syncthreads();
        float invb = 1.0f / (float)boundp[0];
        int NG = (N + 3) >> 2; // 4-point groups
        for (int g = b * BTS + threadIdx.x; g < NG; g += NB * BTS) {
            int n0 = g << 2;
            if (n0 + 4 <= N) {
                f32x4 qa = *(const f32x4*)(xyz + (size_t)n0 * 3);
                f32x4 qb = *(const f32x4*)(xyz + (size_t)n0 * 3 + 4);
                f32x4 qc = *(const f32x4*)(xyz + (size_t)n0 * 3 + 8);
                atomicAdd(&h[morton21(qa.x * invb, qa.y * invb, qa.z * invb) >> 12], 1u);
                atomicAdd(&h[morton21(qa.w * invb, qb.x * invb, qb.y * invb) >> 12], 1u);
                atomicAdd(&h[morton21(qb.z * invb, qb.w * invb, qc.x * invb) >> 12], 1u);
                atomicAdd(&h[morton21(qc.y * invb, qc.z * invb, qc.w * invb) >> 12], 1u);
            } else {
                for (int n = n0; n < N; ++n) {
                    float x = xyz[(size_t)3 * n + 0] * invb;
                    float y = xyz[(size_t)3 * n + 1] * invb;
                    float z = xyz[(size_t)3 * n + 2] * invb;
                    atomicAdd(&h[morton21(x, y, z) >> 12], 1u);
                }
            }
        }
        __syncthreads();
        for (int i = threadIdx.x; i < NBUCK; i += BTS)
            hmat[(size_t)i * NB + b] = h[i];
    } else {
        transpose_tile(b - NB, Lg, Hp, gclb, pclb, stage);
    }
}

// ---------- per-bucket cross-block prefix: 512 one-wave blocks ----------
// Block = bucket. Coalesced 1KB wave read (lane l -> uint4 at l*16), in-lane
// serial over 4, cross-lane exclusive via shfl_up scan. No LDS, no barriers.
// (Replaces the single-block offsets_k whose lane stride was 1KB = uncoalesced.)
__global__ __launch_bounds__(64) void colpfx_k(unsigned* __restrict__ hmat,
                                               unsigned* __restrict__ tt) {
    int bucket = blockIdx.x;
    int lane = threadIdx.x;
    u32x4* row = (u32x4*)(hmat + (size_t)bucket * NB);
    u32x4 q = row[lane];
    unsigned sum = q.x + q.y + q.z + q.w;
    unsigned inc = sum;
#pragma unroll
    for (int o = 1; o < 64; o <<= 1) {
        unsigned v = __shfl_up(inc, o, 64);
        if (lane >= o) inc += v;
    }
    unsigned base = inc - sum; // exclusive lane base
    u32x4 o4;
    o4.x = base; base += q.x;
    o4.y = base; base += q.y;
    o4.z = base; base += q.z;
    o4.w = base;
    row[lane] = o4;
    if (lane == 63) tt[bucket] = inc; // bucket total
}

// Tiny single-block scan of 512 bucket totals -> exclusive bases bb[NBUCK+1].
__global__ __launch_bounds__(NBUCK) void scan_k(const unsigned* __restrict__ tt,
                                                unsigned* __restrict__ bb) {
    __shared__ unsigned tot[NBUCK];
    int t = threadIdx.x;
    unsigned own = tt[t];
    tot[t] = own;
    __syncthreads();
    for (int o = 1; o < NBUCK; o <<= 1) {
        unsigned v = (t >= o) ? tot[t - o] : 0u;
        __syncthreads();
        tot[t] += v;
        __syncthreads();
    }
    bb[t] = tot[t] - own;
    if (t == NBUCK - 1) bb[NBUCK] = tot[t];
}

// ---------- k3: blocks [0,NB) = scatter; rest = transpose tiles [TILES_A,...) ----
// Scatter seed = hmat (per-bucket cross-block prefix) + bb (global bucket base):
// the base-add pass of the old offsets_k is folded into this load.
__global__ __launch_bounds__(BTS) void prep2_k(const float* __restrict__ xyz,
                                               const int* __restrict__ boundp,
                                               const float* __restrict__ Lg,
                                               const float* __restrict__ Hp,
                                               const unsigned* __restrict__ hmat,
                                               const unsigned* __restrict__ bb,
                                               float4* __restrict__ s1,
                                               u32x4* __restrict__ gclb,
                                               u32x4* __restrict__ pclb, int N) {
    __shared__ float stage[8 * TELEM]; // 64 KB; scatter branch aliases first 2KB
    int b = blockIdx.x;
    if (b < NB) {
        unsigned* cnt = (unsigned*)stage;
        for (int i = threadIdx.x; i < NBUCK; i += BTS)
            cnt[i] = hmat[(size_t)i * NB + b] + bb[i];
        __syncthreads();
        float invb = 1.0f / (float)boundp[0];
        int NG = (N + 3) >> 2;
        for (int g = b * BTS + threadIdx.x; g < NG; g += NB * BTS) {
            int n0 = g << 2;
            if (n0 + 4 <= N) {
                f32x4 qa = *(const f32x4*)(xyz + (size_t)n0 * 3);
                f32x4 qb = *(const f32x4*)(xyz + (size_t)n0 * 3 + 4);
                f32x4 qc = *(const f32x4*)(xyz + (size_t)n0 * 3 + 8);
                {
                    float x = qa.x * invb, y = qa.y * invb, z = qa.z * invb;
                    unsigned d = atomicAdd(&cnt[morton21(x, y, z) >> 12], 1u);
                    s1[d] = make_float4(x, y, z, __int_as_float(n0 + 0));
                }
                {
                    float x = qa.w * invb, y = qb.x * invb, z = qb.y * invb;
                    unsigned d = atomicAdd(&cnt[morton21(x, y, z) >> 12], 1u);
                    s1[d] = make_float4(x, y, z, __int_as_float(n0 + 1));
                }
                {
                    float x = qb.z * invb, y = qb.w * invb, z = qc.x * invb;
                    unsigned d = atomicAdd(&cnt[morton21(x, y, z) >> 12], 1u);
                    s1[d] = make_float4(x, y, z, __int_as_float(n0 + 2));
                }
                {
                    float x = qc.y * invb, y = qc.z * invb, z = qc.w * invb;
                    unsigned d = atomicAdd(&cnt[morton21(x, y, z) >> 12], 1u);
                    s1[d] = make_float4(x, y, z, __int_as_float(n0 + 3));
                }
            } else {
                for (int n = n0; n < N; ++n) {
                    float x = xyz[(size_t)3 * n + 0] * invb;
                    float y = xyz[(size_t)3 * n + 1] * invb;
                    float z = xyz[(size_t)3 * n + 2] * invb;
                    unsigned d = atomicAdd(&cnt[morton21(x, y, z) >> 12], 1u);
                    s1[d] = make_float4(x, y, z, __int_as_float(n));
                }
            }
        }
    } else {
        transpose_tile(TILES_A + (b - NB), Lg, Hp, gclb, pclb, stage);
    }
}

// Per-bucket LDS counting sort by fine 12-bit Morton key -> full 128^3 order.
// Records live in registers; LDS only holds the 4096 counters + scan aux.
__global__ __launch_bounds__(1024) void refine_k(const float4* __restrict__ s1,
                                                 const unsigned* __restrict__ bb,
                                                 float4* __restrict__ s2) {
    __shared__ unsigned hist[4096];
    __shared__ unsigned part[1024];
    int b = blockIdx.x;
    unsigned start = bb[b];
    unsigned cnt = bb[b + 1] - start;
    int t = threadIdx.x;
    if (cnt > RCAP) { // statistically unreachable; correctness fallback
        for (unsigned j = t; j < cnt; j += 1024) s2[start + j] = s1[start + j];
        return;
    }
    for (int i = t; i < 4096; i += 1024) hist[i] = 0u;
    __syncthreads();
    float4 rec[RCAP / 1024];
    unsigned key[RCAP / 1024], tick[RCAP / 1024];
#pragma unroll
    for (int k = 0; k < RCAP / 1024; ++k) {
        unsigned j = t + k * 1024u;
        if (j < cnt) {
            rec[k] = s1[start + j];
            key[k] = morton21(rec[k].x, rec[k].y, rec[k].z) & 4095u;
            tick[k] = atomicAdd(&hist[key[k]], 1u);
        }
    }
    __syncthreads();
    unsigned h4[4];
    unsigned s = 0;
#pragma unroll
    for (int k = 0; k < 4; ++k) {
        h4[k] = hist[t * 4 + k];
        s += h4[k];
    }
    part[t] = s;
    __syncthreads();
    for (int o = 1; o < 1024; o <<= 1) {
        unsigned v = (t >= o) ? part[t - o] : 0u;
        __syncthreads();
        part[t] += v;
        __syncthreads();
    }
    unsigned base = part[t] - s;
#pragma unroll
    for (int k = 0; k < 4; ++k) {
        hist[t * 4 + k] = base;
        base += h4[k];
    }
    __syncthreads();
#pragma unroll
    for (int k = 0; k < RCAP / 1024; ++k) {
        unsigned j = t + k * 1024u;
        if (j < cnt) s2[start + hist[key[k]] + tick[k]] = rec[k];
    }
}

// ---------- main sampler (Morton order, bf16 channels-last tables) ----------
// Small blocks dispatched in sorted order = moving window over the tables ->
// near-compulsory FETCH (123MB measured R2). Plain out stores (L2 merges the
// scattered 32B writes to ~63MB; NT stores amplified 8.8x in R3).
__global__ __launch_bounds__(256) void sample_srt(const float4* __restrict__ sorted,
                                                  const uint4* __restrict__ gclb,
                                                  const uint4* __restrict__ pclb,
                                                  float* __restrict__ out, int N) {
    int i = blockIdx.x * blockDim.x + threadIdx.x;
    if (i >= N) return;
    float4 rec = sorted[i];
    float x = rec.x, y = rec.y, z = rec.z;
    int idx = __float_as_int(rec.w);

    int x0, x1, y0, y1, z0, z1;
    float wx, wy, wz;
    to_idx(x, LRES, x0, x1, wx);
    to_idx(y, LRES, y0, y1, wy);
    to_idx(z, LRES, z0, z1, wz);
    const uint4* b00 = gclb + ((size_t)z0 * LRES + y0) * LRES;
    const uint4* b01 = gclb + ((size_t)z0 * LRES + y1) * LRES;
    const uint4* b10 = gclb + ((size_t)z1 * LRES + y0) * LRES;
    const uint4* b11 = gclb + ((size_t)z1 * LRES + y1) * LRES;
    uint4 g0 = b00[x0], g1 = b00[x1], g2 = b01[x0], g3 = b01[x1];
    uint4 g4 = b10[x0], g5 = b10[x1], g6 = b11[x0], g7 = b11[x1];

    const float cw[3] = {x, y, z};
    const float ch[3] = {y, z, x};
    float pww[3], pwh[3];
    uint4 r[12];
#pragma unroll
    for (int p = 0; p < 3; ++p) {
        int w0, w1, h0, h1;
        to_idx(cw[p], HRES, w0, w1, pww[p]);
        to_idx(ch[p], HRES, h0, h1, pwh[p]);
        const uint4* base = pclb + (size_t)p * PPIX;
        const uint4* r0 = base + (size_t)h0 * HRES;
        const uint4* r1 = base + (size_t)h1 * HRES;
        r[4 * p + 0] = r0[w0];
        r[4 * p + 1] = r0[w1];
        r[4 * p + 2] = r1[w0];
        r[4 * p + 3] = r1[w1];
    }

    f32x4 a0 = (f32x4)0.f;
    f32x4 a1 = (f32x4)0.f;
    {
        float ux = 1.f - wx, uy = 1.f - wy, uz = 1.f - wz;
        fma8u(a0, a1, g0, uz * uy * ux);
        fma8u(a0, a1, g1, uz * uy * wx);
        fma8u(a0, a1, g2, uz * wy * ux);
        fma8u(a0, a1, g3, uz * wy * wx);
        fma8u(a0, a1, g4, wz * uy * ux);
        fma8u(a0, a1, g5, wz * uy * wx);
        fma8u(a0, a1, g6, wz * wy * ux);
        fma8u(a0, a1, g7, wz * wy * wx);
    }
#pragma unroll
    for (int p = 0; p < 3; ++p) {
        float ww = pww[p], wh = pwh[p];
        float uw = 1.f - ww, uh = 1.f - wh;
        fma8u(a0, a1, r[4 * p + 0], uh * uw);
        fma8u(a0, a1, r[4 * p + 1], uh * ww);
        fma8u(a0, a1, r[4 * p + 2], wh * uw);
        fma8u(a0, a1, r[4 * p + 3], wh * ww);
    }

    f32x4* o = (f32x4*)(out + (size_t)idx * 8);
    o[0] = a0;
    o[1] = a1;
}

// ---------- fallback (channel-first fp32 direct, known-correct) ----------
__global__ __launch_bounds__(256) void sample_cf(
    const float* __restrict__ xyz, const int* __restrict__ boundp,
    const float* __restrict__ Lg, const float* __restrict__ Hp,
    float* __restrict__ out, int N) {
    int n = blockIdx.x * blockDim.x + threadIdx.x;
    if (n >= N) return;
    float invb = 1.0f / (float)boundp[0];
    float x = xyz[(size_t)3 * n + 0] * invb;
    float y = xyz[(size_t)3 * n + 1] * invb;
    float z = xyz[(size_t)3 * n + 2] * invb;
    float acc[8];
#pragma unroll
    for (int c = 0; c < 8; ++c) acc[c] = 0.f;
    {
        int x0, x1, y0, y1, z0, z1;
        float wx, wy, wz;
        to_idx(x, LRES, x0, x1, wx);
        to_idx(y, LRES, y0, y1, wy);
        to_idx(z, LRES, z0, z1, wz);
        float ux = 1.f - wx, uy = 1.f - wy, uz = 1.f - wz;
        size_t i8[8];
        i8[0] = ((size_t)z0 * LRES + y0) * LRES + x0;
        i8[1] = ((size_t)z0 * LRES + y0) * LRES + x1;
        i8[2] = ((size_t)z0 * LRES + y1) * LRES + x0;
        i8[3] = ((size_t)z0 * LRES + y1) * LRES + x1;
        i8[4] = ((size_t)z1 * LRES + y0) * LRES + x0;
        i8[5] = ((size_t)z1 * LRES + y0) * LRES + x1;
        i8[6] = ((size_t)z1 * LRES + y1) * LRES + x0;
        i8[7] = ((size_t)z1 * LRES + y1) * LRES + x1;
        float w8[8] = {uz * uy * ux, uz * uy * wx, uz * wy * ux, uz * wy * wx,
                       wz * uy * ux, wz * uy * wx, wz * wy * ux, wz * wy * wx};
#pragma unroll
        for (int c = 0; c < 8; ++c) {
            const float* g = Lg + (size_t)c * LVOX;
            float s = 0.f;
#pragma unroll
            for (int k = 0; k < 8; ++k) s = fmaf(g[i8[k]], w8[k], s);
            acc[c] += s;
        }
    }
    {
        const float cw[3] = {x, y, z};
        const float ch[3] = {y, z, x};
        for (int p = 0; p < 3; ++p) {
            int w0, w1, h0, h1;
            float ww, wh;
            to_idx(cw[p], HRES, w0, w1, ww);
            to_idx(ch[p], HRES, h0, h1, wh);
            float uw = 1.f - ww, uh = 1.f - wh;
            size_t i4[4] = {(size_t)h0 * HRES + w0, (size_t)h0 * HRES + w1,
                            (size_t)h1 * HRES + w0, (size_t)h1 * HRES + w1};
            float w4[4] = {uh * uw, uh * ww, wh * uw, wh * ww};
            const float* pb = Hp + (size_t)p * 8 * PPIX;
#pragma unroll
            for (int c = 0; c < 8; ++c) {
                const float* g = pb + (size_t)c * PPIX;
                float s = 0.f;
#pragma unroll
                for (int k = 0; k < 4; ++k) s = fmaf(g[i4[k]], w4[k], s);
                acc[c] += s;
            }
        }
    }
#pragma unroll
    for (int c = 0; c < 8; ++c) out[(size_t)n * 8 + c] = acc[c];
}

extern "C" void kernel_launch(void* const* d_in, const int* in_sizes, int n_in,
                              void* d_out, int out_size, void* d_ws, size_t ws_size,
                              hipStream_t stream) {
    const float* xyz = (const float*)d_in[0];
    const int* bound = (const int*)d_in[1];
    const float* Lg = (const float*)d_in[2]; // [8,128,128,128]
    const float* Hp = (const float*)d_in[3]; // [3,8,1024,1024]
    float* out = (float*)d_out;
    int N = in_sizes[0] / 3;

    size_t off = 0;
    size_t gclb_b = (size_t)LVOX * 16;         // 32 MiB
    size_t pclb_b = (size_t)3 * PPIX * 16;     // 48 MiB
    size_t s1_b = (size_t)N * 16;              // 32 MB
    size_t s2_b = (size_t)N * 16;              // 32 MB
    size_t hmat_b = (size_t)NB * NBUCK * 4;    // 512 KiB
    size_t bb_b = (size_t)(NBUCK + 1) * 4;
    size_t tt_b = (size_t)NBUCK * 4;
    size_t need = gclb_b + pclb_b + s1_b + s2_b + hmat_b + bb_b + tt_b;

    if (ws_size >= need) {
        char* w = (char*)d_ws;
        u32x4* gclb = (u32x4*)(w + off);       off += gclb_b;
        u32x4* pclb = (u32x4*)(w + off);       off += pclb_b;
        float4* s1 = (float4*)(w + off);       off += s1_b;
        float4* s2 = (float4*)(w + off);       off += s2_b;
        unsigned* hmat = (unsigned*)(w + off); off += hmat_b;
        unsigned* bb = (unsigned*)(w + off);   off += bb_b;
        unsigned* tt = (unsigned*)(w + off);

        prep1_k<<<NB + TILES_A, BTS, 0, stream>>>(xyz, bound, Lg, Hp, hmat,
                                                  gclb, pclb, N);
        colpfx_k<<<NBUCK, 64, 0, stream>>>(hmat, tt);
        scan_k<<<1, NBUCK, 0, stream>>>(tt, bb);
        prep2_k<<<NB + TILES_B, BTS, 0, stream>>>(xyz, bound, Lg, Hp, hmat, bb,
                                                  s1, gclb, pclb, N);
        refine_k<<<NBUCK, 1024, 0, stream>>>(s1, bb, s2);
        sample_srt<<<(N + 255) / 256, 256, 0, stream>>>(s2, (const uint4*)gclb,
                                                        (const uint4*)pclb, out, N);
    } else {
        sample_cf<<<(N + 255) / 256, 256, 0, stream>>>(xyz, bound, Lg, Hp, out, N);
    }
}